// Round 14
// baseline (213.013 us; speedup 1.0000x reference)
//
#include <hip/hip_runtime.h>
#include <hip/hip_bf16.h>
#include <math.h>

// qkv_attn: x[8,16384,256] fp32. kv = LN(k)^T LN(v)/HW folded into Wq (per batch).
// R14: k1a = R13 structure with (1) preload arrays removed (in-loop weight loads,
// like best-measured k3 — R5 showed forced preloads pessimize scheduling) and
// (2) atomic-free kv partials (per-block coalesced store; k2 reduces 256 partials).
// k3 unchanged from R8/R13.

#define EPSF 1e-5f

typedef __bf16 bf16x8 __attribute__((ext_vector_type(8)));
typedef __bf16 bf16x4 __attribute__((ext_vector_type(4)));
typedef float  f32x4  __attribute__((ext_vector_type(4)));

// ---------------- K0: weight prep (fp32 -> bf16, de-interleave k/v rows) ----------------
__global__ void k0_prep(const float* __restrict__ Wqkv, const float* __restrict__ Wproj,
                        __bf16* __restrict__ Wkv, __bf16* __restrict__ Wp) {
  int idx = blockIdx.x * 256 + threadIdx.x;   // grid 512*256 = 131072
  {
    int r = idx >> 8, c = idx & 255;
    int half = r >> 8;          // 0:k 1:v
    int rr = r & 255;
    int h = rr >> 4, d = rr & 15;
    Wkv[idx] = (__bf16)Wqkv[(h*48 + 16 + half*16 + d)*256 + c];
  }
  if (idx < 65536) Wp[idx] = (__bf16)Wproj[idx];
}

// ---------------- K1a: k,v GEMM + LN + kv partials (R13 minus preloads, minus atomics) ----
__launch_bounds__(512, 4)
__global__ void k1a(const float* __restrict__ x, const __bf16* __restrict__ Wkv,
                    const float* __restrict__ bqkv,
                    const float* __restrict__ klnw, const float* __restrict__ klnb,
                    const float* __restrict__ vlnw, const float* __restrict__ vlnb,
                    float* __restrict__ part) {
  __shared__ __align__(16) char smem[70656];   // xs[64][264] (33792) | tTk 8x[32][72] (36864)
  __bf16 (*xs)[264] = reinterpret_cast<__bf16(*)[264]>(smem);
  const int tid = threadIdx.x;
  const int w = tid >> 6, l = tid & 63, lr = l & 15, g = l >> 4;
  __bf16 (*tTk)[72] = reinterpret_cast<__bf16(*)[72]>(smem + 33792 + w*4608); // [c 32][r 72]
  __bf16 (*tTv)[64] = reinterpret_cast<__bf16(*)[64]>(smem + w*4096);         // [c 32][r 64] swz

  const long row0 = (long)blockIdx.x * 64;

  #pragma unroll
  for (int i = 0; i < 8; ++i) {
    int idx = tid + i*512;
    int r = idx >> 6, c4 = (idx & 63) << 2;
    f32x4 v = *reinterpret_cast<const f32x4*>(x + (row0 + r)*256 + c4);
    bf16x4 pk; pk[0]=(__bf16)v[0]; pk[1]=(__bf16)v[1]; pk[2]=(__bf16)v[2]; pk[3]=(__bf16)v[3];
    *reinterpret_cast<bf16x4*>(&xs[r][c4]) = pk;
  }
  __syncthreads();

  // ---- pass 0 (k) GEMM: in-loop weight loads (no preload arrays) ----
  f32x4 acc[2][4];
  for (int cb=0;cb<2;cb++) for (int rb=0;rb<4;rb++)
    for (int j=0;j<4;j++) acc[cb][rb][j]=0.f;
  #pragma unroll
  for (int kc = 0; kc < 8; ++kc) {
    const int kb = kc*32 + g*8;
    bf16x8 wfr[2], bf_[4];
    #pragma unroll
    for (int cb=0;cb<2;cb++)
      wfr[cb] = *reinterpret_cast<const bf16x8*>(Wkv + (size_t)(w*32 + cb*16 + lr)*256 + kb);
    #pragma unroll
    for (int rb=0;rb<4;rb++)
      bf_[rb] = *reinterpret_cast<const bf16x8*>(&xs[rb*16+lr][kb]);
    #pragma unroll
    for (int cb=0;cb<2;cb++)
      #pragma unroll
      for (int rb=0;rb<4;rb++)
        acc[cb][rb] = __builtin_amdgcn_mfma_f32_16x16x32_bf16(wfr[cb], bf_[rb], acc[cb][rb], 0,0,0);
  }

  // ---- pass 0 LN-k -> tTk (private region, no barrier needed) ----
  #pragma unroll
  for (int cb=0;cb<2;cb++) {
    const int h = 2*w + cb;
    const f32x4 bb  = *reinterpret_cast<const f32x4*>(bqkv + h*48 + 16 + 4*g);
    const f32x4 lwv = *reinterpret_cast<const f32x4*>(klnw + h*16 + 4*g);
    const f32x4 lbv = *reinterpret_cast<const f32x4*>(klnb + h*16 + 4*g);
    #pragma unroll
    for (int rb=0;rb<4;rb++) {
      float v0 = acc[cb][rb][0] + bb[0];
      float v1 = acc[cb][rb][1] + bb[1];
      float v2 = acc[cb][rb][2] + bb[2];
      float v3 = acc[cb][rb][3] + bb[3];
      float sum = v0+v1+v2+v3;
      sum += __shfl_xor(sum, 16); sum += __shfl_xor(sum, 32);
      const float mu = sum * 0.0625f;
      const float d0=v0-mu, d1=v1-mu, d2=v2-mu, d3=v3-mu;
      float q = d0*d0 + d1*d1 + d2*d2 + d3*d3;
      q += __shfl_xor(q, 16); q += __shfl_xor(q, 32);
      const float sc = __frsqrt_rn(q * (1.f/15.f));   // 1/(std+eps) ~ rsqrt(var)
      const int rr = rb*16 + lr;
      tTk[cb*16 + 4*g+0][rr] = (__bf16)(lwv[0]*d0*sc + lbv[0]);
      tTk[cb*16 + 4*g+1][rr] = (__bf16)(lwv[1]*d1*sc + lbv[1]);
      tTk[cb*16 + 4*g+2][rr] = (__bf16)(lwv[2]*d2*sc + lbv[2]);
      tTk[cb*16 + 4*g+3][rr] = (__bf16)(lwv[3]*d3*sc + lbv[3]);
    }
  }

  // ---- pass 1 (v) GEMM: in-loop weight loads ----
  for (int cb=0;cb<2;cb++) for (int rb=0;rb<4;rb++)
    for (int j=0;j<4;j++) acc[cb][rb][j]=0.f;
  #pragma unroll
  for (int kc = 0; kc < 8; ++kc) {
    const int kb = kc*32 + g*8;
    bf16x8 wfr[2], bf_[4];
    #pragma unroll
    for (int cb=0;cb<2;cb++)
      wfr[cb] = *reinterpret_cast<const bf16x8*>(Wkv + (size_t)(256 + w*32 + cb*16 + lr)*256 + kb);
    #pragma unroll
    for (int rb=0;rb<4;rb++)
      bf_[rb] = *reinterpret_cast<const bf16x8*>(&xs[rb*16+lr][kb]);
    #pragma unroll
    for (int cb=0;cb<2;cb++)
      #pragma unroll
      for (int rb=0;rb<4;rb++)
        acc[cb][rb] = __builtin_amdgcn_mfma_f32_16x16x32_bf16(wfr[cb], bf_[rb], acc[cb][rb], 0,0,0);
  }

  // ---- LN-v arithmetic hoisted above the barrier (R13); results in packed regs ----
  bf16x4 vpk[2][4];
  #pragma unroll
  for (int cb=0;cb<2;cb++) {
    const int h = 2*w + cb;
    const f32x4 bb  = *reinterpret_cast<const f32x4*>(bqkv + h*48 + 32 + 4*g);
    const f32x4 lwv = *reinterpret_cast<const f32x4*>(vlnw + h*16 + 4*g);
    const f32x4 lbv = *reinterpret_cast<const f32x4*>(vlnb + h*16 + 4*g);
    #pragma unroll
    for (int rb=0;rb<4;rb++) {
      float v0 = acc[cb][rb][0] + bb[0];
      float v1 = acc[cb][rb][1] + bb[1];
      float v2 = acc[cb][rb][2] + bb[2];
      float v3 = acc[cb][rb][3] + bb[3];
      float sum = v0+v1+v2+v3;
      sum += __shfl_xor(sum, 16); sum += __shfl_xor(sum, 32);
      const float mu = sum * 0.0625f;
      const float d0=v0-mu, d1=v1-mu, d2=v2-mu, d3=v3-mu;
      float q = d0*d0 + d1*d1 + d2*d2 + d3*d3;
      q += __shfl_xor(q, 16); q += __shfl_xor(q, 32);
      const float sc = __frsqrt_rn(q * (1.f/15.f));
      vpk[cb][rb][0] = (__bf16)(lwv[0]*d0*sc + lbv[0]);
      vpk[cb][rb][1] = (__bf16)(lwv[1]*d1*sc + lbv[1]);
      vpk[cb][rb][2] = (__bf16)(lwv[2]*d2*sc + lbv[2]);
      vpk[cb][rb][3] = (__bf16)(lwv[3]*d3*sc + lbv[3]);
    }
  }

  __syncthreads();   // WAR: all waves done reading xs; its space becomes tTv

  #pragma unroll
  for (int cb=0;cb<2;cb++) {
    #pragma unroll
    for (int rb=0;rb<4;rb++) {
      const int rr = rb*16 + lr;
      tTv[cb*16 + 4*g+0][rr ^ (((4*g+0)&7)<<3)] = vpk[cb][rb][0];
      tTv[cb*16 + 4*g+1][rr ^ (((4*g+1)&7)<<3)] = vpk[cb][rb][1];
      tTv[cb*16 + 4*g+2][rr ^ (((4*g+2)&7)<<3)] = vpk[cb][rb][2];
      tTv[cb*16 + 4*g+3][rr ^ (((4*g+3)&7)<<3)] = vpk[cb][rb][3];
    }
  }

  // ---- kv = k'^T v' (2 MFMAs/head), NON-ATOMIC partial store ----
  #pragma unroll
  for (int hh=0; hh<2; ++hh) {
    f32x4 c; c[0]=0.f; c[1]=0.f; c[2]=0.f; c[3]=0.f;
    #pragma unroll
    for (int ch=0; ch<2; ++ch) {
      const int s = ch*32 + g*8;
      bf16x8 a  = *reinterpret_cast<const bf16x8*>(&tTk[hh*16 + lr][s]);
      bf16x8 bv = *reinterpret_cast<const bf16x8*>(&tTv[hh*16 + lr][s ^ ((lr&7)<<3)]);
      c = __builtin_amdgcn_mfma_f32_16x16x32_bf16(a, bv, c, 0,0,0);
    }
    float* dst = part + ((size_t)blockIdx.x*16 + 2*w + hh)*256;
    #pragma unroll
    for (int j=0;j<4;j++)
      dst[(4*g+j)*16 + lr] = c[j];   // kv[d=4g+j][e=lr] partial for this 64-row tile
  }
}

// ---------------- K2: reduce 256 per-block partials; build Wq_eff and beff --------------
__global__ void k2_weff(const float* __restrict__ Wqkv, const float* __restrict__ bqkv,
                        const float* __restrict__ part,
                        __bf16* __restrict__ Wqe, float* __restrict__ beff) {
  const int b = blockIdx.x >> 4, h = blockIdx.x & 15;
  const int c = threadIdx.x;
  __shared__ float kvs[16][16]; // [d][e]
  const float* base = part + ((size_t)(b*256)*16 + h)*256 + c;
  float a0=0.f, a1=0.f, a2=0.f, a3=0.f;
  #pragma unroll 8
  for (int i=0;i<256;i+=4) {
    a0 += base[(size_t)(i+0)*4096];
    a1 += base[(size_t)(i+1)*4096];
    a2 += base[(size_t)(i+2)*4096];
    a3 += base[(size_t)(i+3)*4096];
  }
  kvs[c >> 4][c & 15] = ((a0+a1)+(a2+a3)) * (1.f/16384.f);
  __syncthreads();
  #pragma unroll 4
  for (int e=0;e<16;e++) {
    float acc = 0.f;
    #pragma unroll
    for (int d=0; d<16; d++)
      acc += kvs[d][e] * Wqkv[(h*48 + d)*256 + c];
    Wqe[((size_t)b*256 + h*16 + e)*256 + c] = (__bf16)acc;
  }
  if (c < 16) {
    float acc = 0.f;
    #pragma unroll
    for (int d=0; d<16; d++) acc += kvs[d][c] * bqkv[h*48 + d];
    beff[b*256 + h*16 + c] = acc;
  }
}

// ---------------- K3: fused o = x@Wq_eff^T; ret = o+beff+x -> rs; proj = ret@Wp^T;
//                  y = gelu(proj+bp) + x(xs), staged through LDS (unchanged R8) ----------
__launch_bounds__(512, 4)
__global__ void k3_fused(const float* __restrict__ x, const __bf16* __restrict__ Wqe,
                         const float* __restrict__ beff, const __bf16* __restrict__ Wp,
                         const float* __restrict__ bproj, float* __restrict__ out) {
  __shared__ __align__(16) __bf16 xs[64][264];
  __shared__ __align__(16) char rsraw[33792];
  __bf16 (*rs)[264] = reinterpret_cast<__bf16(*)[264]>(rsraw);
  float  (*fst)[260] = reinterpret_cast<float(*)[260]>(rsraw);   // 32*260*4 = 33280 <= 33792
  const int tid = threadIdx.x;
  const long browg = (long)blockIdx.x * 64;
  const int b = (int)(browg >> 14);
  const int w = tid>>6, l = tid&63, lr = l&15, g = l>>4;

  #pragma unroll
  for (int i = 0; i < 8; ++i) {
    int idx = tid + i*512;
    int r = idx >> 6, c4 = (idx & 63) << 2;
    f32x4 v = *reinterpret_cast<const f32x4*>(x + (browg + r)*256 + c4);
    bf16x4 pk; pk[0]=(__bf16)v[0]; pk[1]=(__bf16)v[1]; pk[2]=(__bf16)v[2]; pk[3]=(__bf16)v[3];
    *reinterpret_cast<bf16x4*>(&xs[r][c4]) = pk;
  }

  const __bf16* Bq = Wqe + (size_t)b*65536;
  bf16x8 wq[2][8];
  #pragma unroll
  for (int cb=0;cb<2;cb++) {
    const __bf16* wp = Bq + (size_t)(w*32 + cb*16 + lr)*256 + g*8;
    #pragma unroll
    for (int kc=0;kc<8;kc++) wq[cb][kc] = *reinterpret_cast<const bf16x8*>(wp + kc*32);
  }
  __syncthreads();

  f32x4 acc[2][4];
  for (int cb=0;cb<2;cb++) for (int rb=0;rb<4;rb++)
    for (int j=0;j<4;j++) acc[cb][rb][j]=0.f;
  #pragma unroll
  for (int kc=0;kc<8;kc++) {
    const int kb = kc*32 + g*8;
    bf16x8 bf_[4];
    #pragma unroll
    for (int rb=0;rb<4;rb++)
      bf_[rb] = *reinterpret_cast<const bf16x8*>(&xs[rb*16+lr][kb]);
    #pragma unroll
    for (int cb=0;cb<2;cb++)
      #pragma unroll
      for (int rb=0;rb<4;rb++)
        acc[cb][rb] = __builtin_amdgcn_mfma_f32_16x16x32_bf16(wq[cb][kc], bf_[rb], acc[cb][rb], 0,0,0);
  }

  bf16x8 wpj[2][8];
  #pragma unroll
  for (int cb=0;cb<2;cb++) {
    const __bf16* wp = Wp + (size_t)(w*32 + cb*16 + lr)*256 + g*8;
    #pragma unroll
    for (int kc=0;kc<8;kc++) wpj[cb][kc] = *reinterpret_cast<const bf16x8*>(wp + kc*32);
  }

  // ret = o + beff + x -> rs
  #pragma unroll
  for (int cb=0;cb<2;cb++) {
    const int c0 = w*32 + cb*16 + 4*g;
    const f32x4 be = *reinterpret_cast<const f32x4*>(beff + b*256 + c0);
    #pragma unroll
    for (int rb=0;rb<4;rb++) {
      const int r = rb*16 + lr;
      bf16x4 xv = *reinterpret_cast<const bf16x4*>(&xs[r][c0]);
      bf16x4 pk;
      #pragma unroll
      for (int j=0;j<4;j++)
        pk[j] = (__bf16)(acc[cb][rb][j] + be[j] + (float)xv[j]);
      *reinterpret_cast<bf16x4*>(&rs[r][c0]) = pk;
    }
  }
  __syncthreads();

  f32x4 acc2[2][4];
  for (int cb=0;cb<2;cb++) for (int rb=0;rb<4;rb++)
    for (int j=0;j<4;j++) acc2[cb][rb][j]=0.f;
  #pragma unroll
  for (int kc=0;kc<8;kc++) {
    const int kb = kc*32 + g*8;
    bf16x8 bf_[4];
    #pragma unroll
    for (int rb=0;rb<4;rb++)
      bf_[rb] = *reinterpret_cast<const bf16x8*>(&rs[rb*16+lr][kb]);
    #pragma unroll
    for (int cb=0;cb<2;cb++)
      #pragma unroll
      for (int rb=0;rb<4;rb++)
        acc2[cb][rb] = __builtin_amdgcn_mfma_f32_16x16x32_bf16(wpj[cb][kc], bf_[rb], acc2[cb][rb], 0,0,0);
  }
  __syncthreads();   // all GEMM2 reads of rs done; rs region becomes fst

  #pragma unroll
  for (int half=0; half<2; ++half) {
    #pragma unroll
    for (int cb=0;cb<2;cb++) {
      const int c0 = w*32 + cb*16 + 4*g;
      const f32x4 bp4 = *reinterpret_cast<const f32x4*>(bproj + c0);
      #pragma unroll
      for (int rbh=0;rbh<2;rbh++) {
        const int rb = half*2 + rbh;
        const int r = rb*16 + lr;
        bf16x4 xv = *reinterpret_cast<const bf16x4*>(&xs[r][c0]);
        f32x4 o;
        #pragma unroll
        for (int j=0;j<4;j++) {
          float z = acc2[cb][rb][j] + bp4[j];
          o[j] = 0.5f*z*(1.f + erff(z*0.70710678118f)) + (float)xv[j];
        }
        *reinterpret_cast<f32x4*>(&fst[r - half*32][c0]) = o;
      }
    }
    __syncthreads();
    #pragma unroll
    for (int i=0;i<4;i++) {
      int idx = tid + i*512;               // 2048 chunks = 32 rows * 64
      int r32 = idx >> 6, c4 = (idx & 63) << 2;
      f32x4 v = *reinterpret_cast<const f32x4*>(&fst[r32][c4]);
      *reinterpret_cast<f32x4*>(out + (browg + half*32 + r32)*256 + c4) = v;
    }
    if (half == 0) __syncthreads();
  }
}

extern "C" void kernel_launch(void* const* d_in, const int* in_sizes, int n_in,
                              void* d_out, int out_size, void* d_ws, size_t ws_size,
                              hipStream_t stream) {
  const float* x    = (const float*)d_in[0];
  const float* Wqkv = (const float*)d_in[1];
  const float* bqkv = (const float*)d_in[2];
  const float* klnw = (const float*)d_in[3];
  const float* klnb = (const float*)d_in[4];
  const float* vlnw = (const float*)d_in[5];
  const float* vlnb = (const float*)d_in[6];
  const float* Wproj= (const float*)d_in[7];
  const float* bproj= (const float*)d_in[8];
  float* out = (float*)d_out;

  char* ws = (char*)d_ws;
  __bf16* Wkv = (__bf16*)(ws);                 // 512*256*2   = 262144
  __bf16* Wp  = (__bf16*)(ws + 262144);        // 256*256*2   = 131072
  __bf16* Wqe = (__bf16*)(ws + 393216);        // 8*256*256*2 = 1048576
  float*  beff= (float*) (ws + 1441792);       // 8*256*4     = 8192

  // per-block kv partials (2048 x 16 x 256 f32 = 32 MB) at start of d_out;
  // consumed by k2, then k3 fully overwrites d_out (same-stream ordering).
  float* part = (float*)d_out;

  k0_prep <<<512, 256, 0, stream>>>(Wqkv, Wproj, Wkv, Wp);
  k1a     <<<2048, 512, 0, stream>>>(x, Wkv, bqkv, klnw, klnb, vlnw, vlnb, part);
  k2_weff <<<128, 256, 0, stream>>>(Wqkv, bqkv, part, Wqe, beff);
  k3_fused<<<2048, 512, 0, stream>>>(x, Wqe, beff, Wp, bproj, out);
}

// Round 15
// 212.206 us; speedup vs baseline: 1.0038x; 1.0038x over previous
//
#include <hip/hip_runtime.h>
#include <hip/hip_bf16.h>
#include <math.h>

// qkv_attn: x[8,16384,256] fp32. kv = LN(k)^T LN(v)/HW folded into Wq (per batch).
// R15: R13 verbatim (best measured 192.5us) + ONE change: k1a launch_bounds
// (512,4)->(512,3). Occupancy is LDS-capped at 2 blocks/CU either way; relaxing
// the reg cap (128->~170) lets the compiler keep the wk/wv preloads resident and
// schedule deeper (R14 proved the preloads are worth ~27us; VGPR=64 suggests the
// 128-cap was squeezing them).

#define EPSF 1e-5f

typedef __bf16 bf16x8 __attribute__((ext_vector_type(8)));
typedef __bf16 bf16x4 __attribute__((ext_vector_type(4)));
typedef float  f32x4  __attribute__((ext_vector_type(4)));

// ---------------- K0: weight prep (fp32 -> bf16, de-interleave k/v rows), zero kv accum ----
__global__ void k0_prep(const float* __restrict__ Wqkv, const float* __restrict__ Wproj,
                        __bf16* __restrict__ Wkv, __bf16* __restrict__ Wp,
                        float* __restrict__ kv) {
  int idx = blockIdx.x * 256 + threadIdx.x;   // grid 512*256 = 131072
  if (idx < 32768) kv[idx] = 0.f;             // kv accumulator [8][16][16][16]
  {
    int r = idx >> 8, c = idx & 255;
    int half = r >> 8;          // 0:k 1:v
    int rr = r & 255;
    int h = rr >> 4, d = rr & 15;
    Wkv[idx] = (__bf16)Wqkv[(h*48 + 16 + half*16 + d)*256 + c];
  }
  if (idx < 65536) Wp[idx] = (__bf16)Wproj[idx];
}

// ---------------- K1a: k,v GEMM + LN + local kv reduction (R13 + relaxed reg cap) --------
__launch_bounds__(512, 3)
__global__ void k1a(const float* __restrict__ x, const __bf16* __restrict__ Wkv,
                    const float* __restrict__ bqkv,
                    const float* __restrict__ klnw, const float* __restrict__ klnb,
                    const float* __restrict__ vlnw, const float* __restrict__ vlnb,
                    float* __restrict__ kvout) {
  __shared__ __align__(16) char smem[70656];   // xs[64][264] (33792) | tTk 8x[32][72] (36864)
  __bf16 (*xs)[264] = reinterpret_cast<__bf16(*)[264]>(smem);
  const int tid = threadIdx.x;
  const int w = tid >> 6, l = tid & 63, lr = l & 15, g = l >> 4;
  __bf16 (*tTk)[72] = reinterpret_cast<__bf16(*)[72]>(smem + 33792 + w*4608); // [c 32][r 72]
  __bf16 (*tTv)[64] = reinterpret_cast<__bf16(*)[64]>(smem + w*4096);         // [c 32][r 64] swz

  const long row0 = (long)blockIdx.x * 64;
  const int b = (int)(row0 >> 14);

  #pragma unroll
  for (int i = 0; i < 8; ++i) {
    int idx = tid + i*512;
    int r = idx >> 6, c4 = (idx & 63) << 2;
    f32x4 v = *reinterpret_cast<const f32x4*>(x + (row0 + r)*256 + c4);
    bf16x4 pk; pk[0]=(__bf16)v[0]; pk[1]=(__bf16)v[1]; pk[2]=(__bf16)v[2]; pk[3]=(__bf16)v[3];
    *reinterpret_cast<bf16x4*>(&xs[r][c4]) = pk;
  }

  bf16x8 wk[2][8];
  #pragma unroll
  for (int cb=0;cb<2;cb++) {
    const __bf16* wp = Wkv + (size_t)(w*32 + cb*16 + lr)*256 + g*8;
    #pragma unroll
    for (int kc=0;kc<8;kc++) wk[cb][kc] = *reinterpret_cast<const bf16x8*>(wp + kc*32);
  }
  __syncthreads();

  f32x4 acc[2][4];
  for (int cb=0;cb<2;cb++) for (int rb=0;rb<4;rb++)
    for (int j=0;j<4;j++) acc[cb][rb][j]=0.f;
  #pragma unroll
  for (int kc = 0; kc < 8; ++kc) {
    const int kb = kc*32 + g*8;
    bf16x8 bf_[4];
    #pragma unroll
    for (int rb=0;rb<4;rb++)
      bf_[rb] = *reinterpret_cast<const bf16x8*>(&xs[rb*16+lr][kb]);
    #pragma unroll
    for (int cb=0;cb<2;cb++)
      #pragma unroll
      for (int rb=0;rb<4;rb++)
        acc[cb][rb] = __builtin_amdgcn_mfma_f32_16x16x32_bf16(wk[cb][kc], bf_[rb], acc[cb][rb], 0,0,0);
  }

  bf16x8 wv[2][8];
  #pragma unroll
  for (int cb=0;cb<2;cb++) {
    const __bf16* wp = Wkv + (size_t)(256 + w*32 + cb*16 + lr)*256 + g*8;
    #pragma unroll
    for (int kc=0;kc<8;kc++) wv[cb][kc] = *reinterpret_cast<const bf16x8*>(wp + kc*32);
  }

  // ---- pass 0 LN-k -> tTk (private region, no barrier needed) ----
  #pragma unroll
  for (int cb=0;cb<2;cb++) {
    const int h = 2*w + cb;
    const f32x4 bb  = *reinterpret_cast<const f32x4*>(bqkv + h*48 + 16 + 4*g);
    const f32x4 lwv = *reinterpret_cast<const f32x4*>(klnw + h*16 + 4*g);
    const f32x4 lbv = *reinterpret_cast<const f32x4*>(klnb + h*16 + 4*g);
    #pragma unroll
    for (int rb=0;rb<4;rb++) {
      float v0 = acc[cb][rb][0] + bb[0];
      float v1 = acc[cb][rb][1] + bb[1];
      float v2 = acc[cb][rb][2] + bb[2];
      float v3 = acc[cb][rb][3] + bb[3];
      float sum = v0+v1+v2+v3;
      sum += __shfl_xor(sum, 16); sum += __shfl_xor(sum, 32);
      const float mu = sum * 0.0625f;
      const float d0=v0-mu, d1=v1-mu, d2=v2-mu, d3=v3-mu;
      float q = d0*d0 + d1*d1 + d2*d2 + d3*d3;
      q += __shfl_xor(q, 16); q += __shfl_xor(q, 32);
      const float sc = __frsqrt_rn(q * (1.f/15.f));   // 1/(std+eps) ~ rsqrt(var)
      const int rr = rb*16 + lr;
      tTk[cb*16 + 4*g+0][rr] = (__bf16)(lwv[0]*d0*sc + lbv[0]);
      tTk[cb*16 + 4*g+1][rr] = (__bf16)(lwv[1]*d1*sc + lbv[1]);
      tTk[cb*16 + 4*g+2][rr] = (__bf16)(lwv[2]*d2*sc + lbv[2]);
      tTk[cb*16 + 4*g+3][rr] = (__bf16)(lwv[3]*d3*sc + lbv[3]);
    }
  }

  // ---- pass 1 (v) GEMM ----
  for (int cb=0;cb<2;cb++) for (int rb=0;rb<4;rb++)
    for (int j=0;j<4;j++) acc[cb][rb][j]=0.f;
  #pragma unroll
  for (int kc = 0; kc < 8; ++kc) {
    const int kb = kc*32 + g*8;
    bf16x8 bf_[4];
    #pragma unroll
    for (int rb=0;rb<4;rb++)
      bf_[rb] = *reinterpret_cast<const bf16x8*>(&xs[rb*16+lr][kb]);
    #pragma unroll
    for (int cb=0;cb<2;cb++)
      #pragma unroll
      for (int rb=0;rb<4;rb++)
        acc[cb][rb] = __builtin_amdgcn_mfma_f32_16x16x32_bf16(wv[cb][kc], bf_[rb], acc[cb][rb], 0,0,0);
  }

  // ---- LN-v arithmetic hoisted above the barrier: results packed into regs ----
  bf16x4 vpk[2][4];
  #pragma unroll
  for (int cb=0;cb<2;cb++) {
    const int h = 2*w + cb;
    const f32x4 bb  = *reinterpret_cast<const f32x4*>(bqkv + h*48 + 32 + 4*g);
    const f32x4 lwv = *reinterpret_cast<const f32x4*>(vlnw + h*16 + 4*g);
    const f32x4 lbv = *reinterpret_cast<const f32x4*>(vlnb + h*16 + 4*g);
    #pragma unroll
    for (int rb=0;rb<4;rb++) {
      float v0 = acc[cb][rb][0] + bb[0];
      float v1 = acc[cb][rb][1] + bb[1];
      float v2 = acc[cb][rb][2] + bb[2];
      float v3 = acc[cb][rb][3] + bb[3];
      float sum = v0+v1+v2+v3;
      sum += __shfl_xor(sum, 16); sum += __shfl_xor(sum, 32);
      const float mu = sum * 0.0625f;
      const float d0=v0-mu, d1=v1-mu, d2=v2-mu, d3=v3-mu;
      float q = d0*d0 + d1*d1 + d2*d2 + d3*d3;
      q += __shfl_xor(q, 16); q += __shfl_xor(q, 32);
      const float sc = __frsqrt_rn(q * (1.f/15.f));
      vpk[cb][rb][0] = (__bf16)(lwv[0]*d0*sc + lbv[0]);
      vpk[cb][rb][1] = (__bf16)(lwv[1]*d1*sc + lbv[1]);
      vpk[cb][rb][2] = (__bf16)(lwv[2]*d2*sc + lbv[2]);
      vpk[cb][rb][3] = (__bf16)(lwv[3]*d3*sc + lbv[3]);
    }
  }

  __syncthreads();   // WAR: all waves done reading xs; its space becomes tTv

  #pragma unroll
  for (int cb=0;cb<2;cb++) {
    #pragma unroll
    for (int rb=0;rb<4;rb++) {
      const int rr = rb*16 + lr;
      tTv[cb*16 + 4*g+0][rr ^ (((4*g+0)&7)<<3)] = vpk[cb][rb][0];
      tTv[cb*16 + 4*g+1][rr ^ (((4*g+1)&7)<<3)] = vpk[cb][rb][1];
      tTv[cb*16 + 4*g+2][rr ^ (((4*g+2)&7)<<3)] = vpk[cb][rb][2];
      tTv[cb*16 + 4*g+3][rr ^ (((4*g+3)&7)<<3)] = vpk[cb][rb][3];
    }
  }

  #pragma unroll
  for (int hh=0; hh<2; ++hh) {
    f32x4 c; c[0]=0.f; c[1]=0.f; c[2]=0.f; c[3]=0.f;
    #pragma unroll
    for (int ch=0; ch<2; ++ch) {
      const int s = ch*32 + g*8;
      bf16x8 a  = *reinterpret_cast<const bf16x8*>(&tTk[hh*16 + lr][s]);
      bf16x8 bv = *reinterpret_cast<const bf16x8*>(&tTv[hh*16 + lr][s ^ ((lr&7)<<3)]);
      c = __builtin_amdgcn_mfma_f32_16x16x32_bf16(a, bv, c, 0,0,0);
    }
    float* dst = kvout + ((size_t)(b*16 + 2*w + hh) << 8);
    #pragma unroll
    for (int j=0;j<4;j++)
      atomicAdd(dst + (4*g+j)*16 + lr, c[j]);
  }
}

// ---------------- K2: Wq_eff[b][h*16+e][c] = sum_d kv[b,h,d,e]/HW * Wq[h*48+d][c] ----------
__global__ void k2_weff(const float* __restrict__ Wqkv, const float* __restrict__ bqkv,
                        const float* __restrict__ kvin,
                        __bf16* __restrict__ Wqe, float* __restrict__ beff) {
  const int b = blockIdx.x >> 4, h = blockIdx.x & 15;
  const int c = threadIdx.x;
  __shared__ float kvs[16][16]; // [d][e]
  kvs[c >> 4][c & 15] = kvin[(b*16 + h)*256 + c] * (1.f/16384.f);
  __syncthreads();
  #pragma unroll 4
  for (int e=0;e<16;e++) {
    float acc = 0.f;
    #pragma unroll
    for (int d=0; d<16; d++)
      acc += kvs[d][e] * Wqkv[(h*48 + d)*256 + c];
    Wqe[((size_t)b*256 + h*16 + e)*256 + c] = (__bf16)acc;
  }
  if (c < 16) {
    float acc = 0.f;
    #pragma unroll
    for (int d=0; d<16; d++) acc += kvs[d][c] * bqkv[h*48 + d];
    beff[b*256 + h*16 + c] = acc;
  }
}

// ---------------- K3: fused o = x@Wq_eff^T; ret = o+beff+x -> rs; proj = ret@Wp^T;
//                  y = gelu(proj+bp) + x(xs), staged through LDS (unchanged R8) ----------
__launch_bounds__(512, 4)
__global__ void k3_fused(const float* __restrict__ x, const __bf16* __restrict__ Wqe,
                         const float* __restrict__ beff, const __bf16* __restrict__ Wp,
                         const float* __restrict__ bproj, float* __restrict__ out) {
  __shared__ __align__(16) __bf16 xs[64][264];
  __shared__ __align__(16) char rsraw[33792];
  __bf16 (*rs)[264] = reinterpret_cast<__bf16(*)[264]>(rsraw);
  float  (*fst)[260] = reinterpret_cast<float(*)[260]>(rsraw);   // 32*260*4 = 33280 <= 33792
  const int tid = threadIdx.x;
  const long browg = (long)blockIdx.x * 64;
  const int b = (int)(browg >> 14);
  const int w = tid>>6, l = tid&63, lr = l&15, g = l>>4;

  #pragma unroll
  for (int i = 0; i < 8; ++i) {
    int idx = tid + i*512;
    int r = idx >> 6, c4 = (idx & 63) << 2;
    f32x4 v = *reinterpret_cast<const f32x4*>(x + (browg + r)*256 + c4);
    bf16x4 pk; pk[0]=(__bf16)v[0]; pk[1]=(__bf16)v[1]; pk[2]=(__bf16)v[2]; pk[3]=(__bf16)v[3];
    *reinterpret_cast<bf16x4*>(&xs[r][c4]) = pk;
  }

  const __bf16* Bq = Wqe + (size_t)b*65536;
  bf16x8 wq[2][8];
  #pragma unroll
  for (int cb=0;cb<2;cb++) {
    const __bf16* wp = Bq + (size_t)(w*32 + cb*16 + lr)*256 + g*8;
    #pragma unroll
    for (int kc=0;kc<8;kc++) wq[cb][kc] = *reinterpret_cast<const bf16x8*>(wp + kc*32);
  }
  __syncthreads();

  f32x4 acc[2][4];
  for (int cb=0;cb<2;cb++) for (int rb=0;rb<4;rb++)
    for (int j=0;j<4;j++) acc[cb][rb][j]=0.f;
  #pragma unroll
  for (int kc=0;kc<8;kc++) {
    const int kb = kc*32 + g*8;
    bf16x8 bf_[4];
    #pragma unroll
    for (int rb=0;rb<4;rb++)
      bf_[rb] = *reinterpret_cast<const bf16x8*>(&xs[rb*16+lr][kb]);
    #pragma unroll
    for (int cb=0;cb<2;cb++)
      #pragma unroll
      for (int rb=0;rb<4;rb++)
        acc[cb][rb] = __builtin_amdgcn_mfma_f32_16x16x32_bf16(wq[cb][kc], bf_[rb], acc[cb][rb], 0,0,0);
  }

  bf16x8 wpj[2][8];
  #pragma unroll
  for (int cb=0;cb<2;cb++) {
    const __bf16* wp = Wp + (size_t)(w*32 + cb*16 + lr)*256 + g*8;
    #pragma unroll
    for (int kc=0;kc<8;kc++) wpj[cb][kc] = *reinterpret_cast<const bf16x8*>(wp + kc*32);
  }

  // ret = o + beff + x -> rs
  #pragma unroll
  for (int cb=0;cb<2;cb++) {
    const int c0 = w*32 + cb*16 + 4*g;
    const f32x4 be = *reinterpret_cast<const f32x4*>(beff + b*256 + c0);
    #pragma unroll
    for (int rb=0;rb<4;rb++) {
      const int r = rb*16 + lr;
      bf16x4 xv = *reinterpret_cast<const bf16x4*>(&xs[r][c0]);
      bf16x4 pk;
      #pragma unroll
      for (int j=0;j<4;j++)
        pk[j] = (__bf16)(acc[cb][rb][j] + be[j] + (float)xv[j]);
      *reinterpret_cast<bf16x4*>(&rs[r][c0]) = pk;
    }
  }
  __syncthreads();

  f32x4 acc2[2][4];
  for (int cb=0;cb<2;cb++) for (int rb=0;rb<4;rb++)
    for (int j=0;j<4;j++) acc2[cb][rb][j]=0.f;
  #pragma unroll
  for (int kc=0;kc<8;kc++) {
    const int kb = kc*32 + g*8;
    bf16x8 bf_[4];
    #pragma unroll
    for (int rb=0;rb<4;rb++)
      bf_[rb] = *reinterpret_cast<const bf16x8*>(&rs[rb*16+lr][kb]);
    #pragma unroll
    for (int cb=0;cb<2;cb++)
      #pragma unroll
      for (int rb=0;rb<4;rb++)
        acc2[cb][rb] = __builtin_amdgcn_mfma_f32_16x16x32_bf16(wpj[cb][kc], bf_[rb], acc2[cb][rb], 0,0,0);
  }
  __syncthreads();   // all GEMM2 reads of rs done; rs region becomes fst

  #pragma unroll
  for (int half=0; half<2; ++half) {
    #pragma unroll
    for (int cb=0;cb<2;cb++) {
      const int c0 = w*32 + cb*16 + 4*g;
      const f32x4 bp4 = *reinterpret_cast<const f32x4*>(bproj + c0);
      #pragma unroll
      for (int rbh=0;rbh<2;rbh++) {
        const int rb = half*2 + rbh;
        const int r = rb*16 + lr;
        bf16x4 xv = *reinterpret_cast<const bf16x4*>(&xs[r][c0]);
        f32x4 o;
        #pragma unroll
        for (int j=0;j<4;j++) {
          float z = acc2[cb][rb][j] + bp4[j];
          o[j] = 0.5f*z*(1.f + erff(z*0.70710678118f)) + (float)xv[j];
        }
        *reinterpret_cast<f32x4*>(&fst[r - half*32][c0]) = o;
      }
    }
    __syncthreads();
    #pragma unroll
    for (int i=0;i<4;i++) {
      int idx = tid + i*512;               // 2048 chunks = 32 rows * 64
      int r32 = idx >> 6, c4 = (idx & 63) << 2;
      f32x4 v = *reinterpret_cast<const f32x4*>(&fst[r32][c4]);
      *reinterpret_cast<f32x4*>(out + (browg + half*32 + r32)*256 + c4) = v;
    }
    if (half == 0) __syncthreads();
  }
}

extern "C" void kernel_launch(void* const* d_in, const int* in_sizes, int n_in,
                              void* d_out, int out_size, void* d_ws, size_t ws_size,
                              hipStream_t stream) {
  const float* x    = (const float*)d_in[0];
  const float* Wqkv = (const float*)d_in[1];
  const float* bqkv = (const float*)d_in[2];
  const float* klnw = (const float*)d_in[3];
  const float* klnb = (const float*)d_in[4];
  const float* vlnw = (const float*)d_in[5];
  const float* vlnb = (const float*)d_in[6];
  const float* Wproj= (const float*)d_in[7];
  const float* bproj= (const float*)d_in[8];
  float* out = (float*)d_out;

  char* ws = (char*)d_ws;
  __bf16* Wkv = (__bf16*)(ws);                 // 512*256*2   = 262144
  __bf16* Wp  = (__bf16*)(ws + 262144);        // 256*256*2   = 131072
  float*  kv  = (float*) (ws + 393216);        // 32768*4     = 131072
  __bf16* Wqe = (__bf16*)(ws + 524288);        // 8*256*256*2 = 1048576
  float*  beff= (float*) (ws + 1572864);       // 8*256*4     = 8192

  k0_prep <<<512, 256, 0, stream>>>(Wqkv, Wproj, Wkv, Wp, kv);
  k1a     <<<2048, 512, 0, stream>>>(x, Wkv, bqkv, klnw, klnb, vlnw, vlnb, kv);
  k2_weff <<<128, 256, 0, stream>>>(Wqkv, bqkv, kv, Wqe, beff);
  k3_fused<<<2048, 512, 0, stream>>>(x, Wqe, beff, Wp, bproj, out);
}

// Round 16
// 195.952 us; speedup vs baseline: 1.0871x; 1.0830x over previous
//
#include <hip/hip_runtime.h>
#include <hip/hip_bf16.h>
#include <math.h>

// qkv_attn: x[8,16384,256] fp32. kv = LN(k)^T LN(v)/HW folded into Wq (per batch).
// R16: R13 base with k1a restructured to ONE barrier: dual accumulators (acc_k,
// acc_v) + per-head-sequenced private k'/v' tiles inside the existing 4608B/wave
// region (one head's k'[16][72] + v'[16][64] = 4352B fits) -> no xs overlay, no
// WAR barrier. Preloads kept (R14: worth 27us), (512,4) kept (R15: relaxing hurt).
// k0/k2/k3 identical to R13.

#define EPSF 1e-5f

typedef __bf16 bf16x8 __attribute__((ext_vector_type(8)));
typedef __bf16 bf16x4 __attribute__((ext_vector_type(4)));
typedef float  f32x4  __attribute__((ext_vector_type(4)));

// ---------------- K0: weight prep (fp32 -> bf16, de-interleave k/v rows), zero kv accum ----
__global__ void k0_prep(const float* __restrict__ Wqkv, const float* __restrict__ Wproj,
                        __bf16* __restrict__ Wkv, __bf16* __restrict__ Wp,
                        float* __restrict__ kv) {
  int idx = blockIdx.x * 256 + threadIdx.x;   // grid 512*256 = 131072
  if (idx < 32768) kv[idx] = 0.f;             // kv accumulator [8][16][16][16]
  {
    int r = idx >> 8, c = idx & 255;
    int half = r >> 8;          // 0:k 1:v
    int rr = r & 255;
    int h = rr >> 4, d = rr & 15;
    Wkv[idx] = (__bf16)Wqkv[(h*48 + 16 + half*16 + d)*256 + c];
  }
  if (idx < 65536) Wp[idx] = (__bf16)Wproj[idx];
}

// ---------------- K1a: k,v GEMM + LN + kv (ONE barrier, per-head-sequenced tiles) --------
__launch_bounds__(512, 4)
__global__ void k1a(const float* __restrict__ x, const __bf16* __restrict__ Wkv,
                    const float* __restrict__ bqkv,
                    const float* __restrict__ klnw, const float* __restrict__ klnb,
                    const float* __restrict__ vlnw, const float* __restrict__ vlnb,
                    float* __restrict__ kvout) {
  __shared__ __align__(16) char smem[70656];   // xs[64][264] (33792) + 8 x 4608B wave region
  __bf16 (*xs)[264] = reinterpret_cast<__bf16(*)[264]>(smem);
  const int tid = threadIdx.x;
  const int w = tid >> 6, l = tid & 63, lr = l & 15, g = l >> 4;
  char* pw = smem + 33792 + w*4608;
  __bf16 (*tK)[72] = reinterpret_cast<__bf16(*)[72]>(pw);          // one head: k' [16][72]
  __bf16 (*tV)[64] = reinterpret_cast<__bf16(*)[64]>(pw + 2304);   // one head: v' [16][64] swz

  const long row0 = (long)blockIdx.x * 64;
  const int b = (int)(row0 >> 14);

  // stage x tile -> bf16 LDS
  #pragma unroll
  for (int i = 0; i < 8; ++i) {
    int idx = tid + i*512;
    int r = idx >> 6, c4 = (idx & 63) << 2;
    f32x4 v = *reinterpret_cast<const f32x4*>(x + (row0 + r)*256 + c4);
    bf16x4 pk; pk[0]=(__bf16)v[0]; pk[1]=(__bf16)v[1]; pk[2]=(__bf16)v[2]; pk[3]=(__bf16)v[3];
    *reinterpret_cast<bf16x4*>(&xs[r][c4]) = pk;
  }

  // preload pass-0 (k) weights: 16 independent L2 loads in flight during staging
  bf16x8 wk[2][8];
  #pragma unroll
  for (int cb=0;cb<2;cb++) {
    const __bf16* wp = Wkv + (size_t)(w*32 + cb*16 + lr)*256 + g*8;
    #pragma unroll
    for (int kc=0;kc<8;kc++) wk[cb][kc] = *reinterpret_cast<const bf16x8*>(wp + kc*32);
  }
  __syncthreads();   // the ONLY barrier

  // ---- pass 0 (k) GEMM -> acc_k ----
  f32x4 acc_k[2][4];
  for (int cb=0;cb<2;cb++) for (int rb=0;rb<4;rb++)
    for (int j=0;j<4;j++) acc_k[cb][rb][j]=0.f;
  #pragma unroll
  for (int kc = 0; kc < 8; ++kc) {
    const int kb = kc*32 + g*8;
    bf16x8 bf_[4];
    #pragma unroll
    for (int rb=0;rb<4;rb++)
      bf_[rb] = *reinterpret_cast<const bf16x8*>(&xs[rb*16+lr][kb]);
    #pragma unroll
    for (int cb=0;cb<2;cb++)
      #pragma unroll
      for (int rb=0;rb<4;rb++)
        acc_k[cb][rb] = __builtin_amdgcn_mfma_f32_16x16x32_bf16(wk[cb][kc], bf_[rb], acc_k[cb][rb], 0,0,0);
  }

  // preload pass-1 (v) weights; they drain under LN-k(h0)
  bf16x8 wv[2][8];
  #pragma unroll
  for (int cb=0;cb<2;cb++) {
    const __bf16* wp = Wkv + (size_t)(256 + w*32 + cb*16 + lr)*256 + g*8;
    #pragma unroll
    for (int kc=0;kc<8;kc++) wv[cb][kc] = *reinterpret_cast<const bf16x8*>(wp + kc*32);
  }

  // ---- LN-k (head h0 = 2w) -> tK ----
  {
    const int h = 2*w;
    const f32x4 bb  = *reinterpret_cast<const f32x4*>(bqkv + h*48 + 16 + 4*g);
    const f32x4 lwv = *reinterpret_cast<const f32x4*>(klnw + h*16 + 4*g);
    const f32x4 lbv = *reinterpret_cast<const f32x4*>(klnb + h*16 + 4*g);
    #pragma unroll
    for (int rb=0;rb<4;rb++) {
      float v0 = acc_k[0][rb][0] + bb[0];
      float v1 = acc_k[0][rb][1] + bb[1];
      float v2 = acc_k[0][rb][2] + bb[2];
      float v3 = acc_k[0][rb][3] + bb[3];
      float sum = v0+v1+v2+v3;
      sum += __shfl_xor(sum, 16); sum += __shfl_xor(sum, 32);
      const float mu = sum * 0.0625f;
      const float d0=v0-mu, d1=v1-mu, d2=v2-mu, d3=v3-mu;
      float q = d0*d0 + d1*d1 + d2*d2 + d3*d3;
      q += __shfl_xor(q, 16); q += __shfl_xor(q, 32);
      const float sc = __frsqrt_rn(q * (1.f/15.f));   // 1/(std+eps) ~ rsqrt(var)
      const int rr = rb*16 + lr;
      tK[4*g+0][rr] = (__bf16)(lwv[0]*d0*sc + lbv[0]);
      tK[4*g+1][rr] = (__bf16)(lwv[1]*d1*sc + lbv[1]);
      tK[4*g+2][rr] = (__bf16)(lwv[2]*d2*sc + lbv[2]);
      tK[4*g+3][rr] = (__bf16)(lwv[3]*d3*sc + lbv[3]);
    }
  }

  // ---- pass 1 (v) GEMM -> acc_v ----
  f32x4 acc_v[2][4];
  for (int cb=0;cb<2;cb++) for (int rb=0;rb<4;rb++)
    for (int j=0;j<4;j++) acc_v[cb][rb][j]=0.f;
  #pragma unroll
  for (int kc = 0; kc < 8; ++kc) {
    const int kb = kc*32 + g*8;
    bf16x8 bf_[4];
    #pragma unroll
    for (int rb=0;rb<4;rb++)
      bf_[rb] = *reinterpret_cast<const bf16x8*>(&xs[rb*16+lr][kb]);
    #pragma unroll
    for (int cb=0;cb<2;cb++)
      #pragma unroll
      for (int rb=0;rb<4;rb++)
        acc_v[cb][rb] = __builtin_amdgcn_mfma_f32_16x16x32_bf16(wv[cb][kc], bf_[rb], acc_v[cb][rb], 0,0,0);
  }

  // ---- per head: LN-v -> tV, kv MFMA, atomics; head 1 reuses tiles (in-wave WAR) ----
  #pragma unroll
  for (int hh=0; hh<2; ++hh) {
    const int h = 2*w + hh;
    if (hh == 1) {
      // LN-k (head h1) -> tK, overwriting h0's tile (reads for h0 already issued/consumed)
      const f32x4 bb  = *reinterpret_cast<const f32x4*>(bqkv + h*48 + 16 + 4*g);
      const f32x4 lwv = *reinterpret_cast<const f32x4*>(klnw + h*16 + 4*g);
      const f32x4 lbv = *reinterpret_cast<const f32x4*>(klnb + h*16 + 4*g);
      #pragma unroll
      for (int rb=0;rb<4;rb++) {
        float v0 = acc_k[1][rb][0] + bb[0];
        float v1 = acc_k[1][rb][1] + bb[1];
        float v2 = acc_k[1][rb][2] + bb[2];
        float v3 = acc_k[1][rb][3] + bb[3];
        float sum = v0+v1+v2+v3;
        sum += __shfl_xor(sum, 16); sum += __shfl_xor(sum, 32);
        const float mu = sum * 0.0625f;
        const float d0=v0-mu, d1=v1-mu, d2=v2-mu, d3=v3-mu;
        float q = d0*d0 + d1*d1 + d2*d2 + d3*d3;
        q += __shfl_xor(q, 16); q += __shfl_xor(q, 32);
        const float sc = __frsqrt_rn(q * (1.f/15.f));
        const int rr = rb*16 + lr;
        tK[4*g+0][rr] = (__bf16)(lwv[0]*d0*sc + lbv[0]);
        tK[4*g+1][rr] = (__bf16)(lwv[1]*d1*sc + lbv[1]);
        tK[4*g+2][rr] = (__bf16)(lwv[2]*d2*sc + lbv[2]);
        tK[4*g+3][rr] = (__bf16)(lwv[3]*d3*sc + lbv[3]);
      }
    }
    // LN-v (head h) -> tV (XOR-swizzled rows)
    {
      const f32x4 bb  = *reinterpret_cast<const f32x4*>(bqkv + h*48 + 32 + 4*g);
      const f32x4 lwv = *reinterpret_cast<const f32x4*>(vlnw + h*16 + 4*g);
      const f32x4 lbv = *reinterpret_cast<const f32x4*>(vlnb + h*16 + 4*g);
      #pragma unroll
      for (int rb=0;rb<4;rb++) {
        float v0 = acc_v[hh][rb][0] + bb[0];
        float v1 = acc_v[hh][rb][1] + bb[1];
        float v2 = acc_v[hh][rb][2] + bb[2];
        float v3 = acc_v[hh][rb][3] + bb[3];
        float sum = v0+v1+v2+v3;
        sum += __shfl_xor(sum, 16); sum += __shfl_xor(sum, 32);
        const float mu = sum * 0.0625f;
        const float d0=v0-mu, d1=v1-mu, d2=v2-mu, d3=v3-mu;
        float q = d0*d0 + d1*d1 + d2*d2 + d3*d3;
        q += __shfl_xor(q, 16); q += __shfl_xor(q, 32);
        const float sc = __frsqrt_rn(q * (1.f/15.f));
        const int rr = rb*16 + lr;
        tV[4*g+0][rr ^ (((4*g+0)&7)<<3)] = (__bf16)(lwv[0]*d0*sc + lbv[0]);
        tV[4*g+1][rr ^ (((4*g+1)&7)<<3)] = (__bf16)(lwv[1]*d1*sc + lbv[1]);
        tV[4*g+2][rr ^ (((4*g+2)&7)<<3)] = (__bf16)(lwv[2]*d2*sc + lbv[2]);
        tV[4*g+3][rr ^ (((4*g+3)&7)<<3)] = (__bf16)(lwv[3]*d3*sc + lbv[3]);
      }
    }
    // kv_h += k'^T v' (2 MFMAs), atomics
    f32x4 c0; c0[0]=0.f; c0[1]=0.f; c0[2]=0.f; c0[3]=0.f;
    #pragma unroll
    for (int ch=0; ch<2; ++ch) {
      const int s = ch*32 + g*8;
      bf16x8 a  = *reinterpret_cast<const bf16x8*>(&tK[lr][s]);
      bf16x8 bv = *reinterpret_cast<const bf16x8*>(&tV[lr][s ^ ((lr&7)<<3)]);
      c0 = __builtin_amdgcn_mfma_f32_16x16x32_bf16(a, bv, c0, 0,0,0);
    }
    float* dst = kvout + ((size_t)(b*16 + 2*w + hh) << 8);
    #pragma unroll
    for (int j=0;j<4;j++)
      atomicAdd(dst + (4*g+j)*16 + lr, c0[j]);
  }
}

// ---------------- K2: Wq_eff[b][h*16+e][c] = sum_d kv[b,h,d,e]/HW * Wq[h*48+d][c] ----------
__global__ void k2_weff(const float* __restrict__ Wqkv, const float* __restrict__ bqkv,
                        const float* __restrict__ kvin,
                        __bf16* __restrict__ Wqe, float* __restrict__ beff) {
  const int b = blockIdx.x >> 4, h = blockIdx.x & 15;
  const int c = threadIdx.x;
  __shared__ float kvs[16][16]; // [d][e]
  kvs[c >> 4][c & 15] = kvin[(b*16 + h)*256 + c] * (1.f/16384.f);
  __syncthreads();
  #pragma unroll 4
  for (int e=0;e<16;e++) {
    float acc = 0.f;
    #pragma unroll
    for (int d=0; d<16; d++)
      acc += kvs[d][e] * Wqkv[(h*48 + d)*256 + c];
    Wqe[((size_t)b*256 + h*16 + e)*256 + c] = (__bf16)acc;
  }
  if (c < 16) {
    float acc = 0.f;
    #pragma unroll
    for (int d=0; d<16; d++) acc += kvs[d][c] * bqkv[h*48 + d];
    beff[b*256 + h*16 + c] = acc;
  }
}

// ---------------- K3: fused o = x@Wq_eff^T; ret = o+beff+x -> rs; proj = ret@Wp^T;
//                  y = gelu(proj+bp) + x(xs), staged through LDS (unchanged R13) ----------
__launch_bounds__(512, 4)
__global__ void k3_fused(const float* __restrict__ x, const __bf16* __restrict__ Wqe,
                         const float* __restrict__ beff, const __bf16* __restrict__ Wp,
                         const float* __restrict__ bproj, float* __restrict__ out) {
  __shared__ __align__(16) __bf16 xs[64][264];
  __shared__ __align__(16) char rsraw[33792];
  __bf16 (*rs)[264] = reinterpret_cast<__bf16(*)[264]>(rsraw);
  float  (*fst)[260] = reinterpret_cast<float(*)[260]>(rsraw);   // 32*260*4 = 33280 <= 33792
  const int tid = threadIdx.x;
  const long browg = (long)blockIdx.x * 64;
  const int b = (int)(browg >> 14);
  const int w = tid>>6, l = tid&63, lr = l&15, g = l>>4;

  #pragma unroll
  for (int i = 0; i < 8; ++i) {
    int idx = tid + i*512;
    int r = idx >> 6, c4 = (idx & 63) << 2;
    f32x4 v = *reinterpret_cast<const f32x4*>(x + (browg + r)*256 + c4);
    bf16x4 pk; pk[0]=(__bf16)v[0]; pk[1]=(__bf16)v[1]; pk[2]=(__bf16)v[2]; pk[3]=(__bf16)v[3];
    *reinterpret_cast<bf16x4*>(&xs[r][c4]) = pk;
  }

  const __bf16* Bq = Wqe + (size_t)b*65536;
  bf16x8 wq[2][8];
  #pragma unroll
  for (int cb=0;cb<2;cb++) {
    const __bf16* wp = Bq + (size_t)(w*32 + cb*16 + lr)*256 + g*8;
    #pragma unroll
    for (int kc=0;kc<8;kc++) wq[cb][kc] = *reinterpret_cast<const bf16x8*>(wp + kc*32);
  }
  __syncthreads();

  f32x4 acc[2][4];
  for (int cb=0;cb<2;cb++) for (int rb=0;rb<4;rb++)
    for (int j=0;j<4;j++) acc[cb][rb][j]=0.f;
  #pragma unroll
  for (int kc=0;kc<8;kc++) {
    const int kb = kc*32 + g*8;
    bf16x8 bf_[4];
    #pragma unroll
    for (int rb=0;rb<4;rb++)
      bf_[rb] = *reinterpret_cast<const bf16x8*>(&xs[rb*16+lr][kb]);
    #pragma unroll
    for (int cb=0;cb<2;cb++)
      #pragma unroll
      for (int rb=0;rb<4;rb++)
        acc[cb][rb] = __builtin_amdgcn_mfma_f32_16x16x32_bf16(wq[cb][kc], bf_[rb], acc[cb][rb], 0,0,0);
  }

  bf16x8 wpj[2][8];
  #pragma unroll
  for (int cb=0;cb<2;cb++) {
    const __bf16* wp = Wp + (size_t)(w*32 + cb*16 + lr)*256 + g*8;
    #pragma unroll
    for (int kc=0;kc<8;kc++) wpj[cb][kc] = *reinterpret_cast<const bf16x8*>(wp + kc*32);
  }

  // ret = o + beff + x -> rs
  #pragma unroll
  for (int cb=0;cb<2;cb++) {
    const int c0 = w*32 + cb*16 + 4*g;
    const f32x4 be = *reinterpret_cast<const f32x4*>(beff + b*256 + c0);
    #pragma unroll
    for (int rb=0;rb<4;rb++) {
      const int r = rb*16 + lr;
      bf16x4 xv = *reinterpret_cast<const bf16x4*>(&xs[r][c0]);
      bf16x4 pk;
      #pragma unroll
      for (int j=0;j<4;j++)
        pk[j] = (__bf16)(acc[cb][rb][j] + be[j] + (float)xv[j]);
      *reinterpret_cast<bf16x4*>(&rs[r][c0]) = pk;
    }
  }
  __syncthreads();

  f32x4 acc2[2][4];
  for (int cb=0;cb<2;cb++) for (int rb=0;rb<4;rb++)
    for (int j=0;j<4;j++) acc2[cb][rb][j]=0.f;
  #pragma unroll
  for (int kc=0;kc<8;kc++) {
    const int kb = kc*32 + g*8;
    bf16x8 bf_[4];
    #pragma unroll
    for (int rb=0;rb<4;rb++)
      bf_[rb] = *reinterpret_cast<const bf16x8*>(&rs[rb*16+lr][kb]);
    #pragma unroll
    for (int cb=0;cb<2;cb++)
      #pragma unroll
      for (int rb=0;rb<4;rb++)
        acc2[cb][rb] = __builtin_amdgcn_mfma_f32_16x16x32_bf16(wpj[cb][kc], bf_[rb], acc2[cb][rb], 0,0,0);
  }
  __syncthreads();   // all GEMM2 reads of rs done; rs region becomes fst

  #pragma unroll
  for (int half=0; half<2; ++half) {
    #pragma unroll
    for (int cb=0;cb<2;cb++) {
      const int c0 = w*32 + cb*16 + 4*g;
      const f32x4 bp4 = *reinterpret_cast<const f32x4*>(bproj + c0);
      #pragma unroll
      for (int rbh=0;rbh<2;rbh++) {
        const int rb = half*2 + rbh;
        const int r = rb*16 + lr;
        bf16x4 xv = *reinterpret_cast<const bf16x4*>(&xs[r][c0]);
        f32x4 o;
        #pragma unroll
        for (int j=0;j<4;j++) {
          float z = acc2[cb][rb][j] + bp4[j];
          o[j] = 0.5f*z*(1.f + erff(z*0.70710678118f)) + (float)xv[j];
        }
        *reinterpret_cast<f32x4*>(&fst[r - half*32][c0]) = o;
      }
    }
    __syncthreads();
    #pragma unroll
    for (int i=0;i<4;i++) {
      int idx = tid + i*512;               // 2048 chunks = 32 rows * 64
      int r32 = idx >> 6, c4 = (idx & 63) << 2;
      f32x4 v = *reinterpret_cast<const f32x4*>(&fst[r32][c4]);
      *reinterpret_cast<f32x4*>(out + (browg + half*32 + r32)*256 + c4) = v;
    }
    if (half == 0) __syncthreads();
  }
}

extern "C" void kernel_launch(void* const* d_in, const int* in_sizes, int n_in,
                              void* d_out, int out_size, void* d_ws, size_t ws_size,
                              hipStream_t stream) {
  const float* x    = (const float*)d_in[0];
  const float* Wqkv = (const float*)d_in[1];
  const float* bqkv = (const float*)d_in[2];
  const float* klnw = (const float*)d_in[3];
  const float* klnb = (const float*)d_in[4];
  const float* vlnw = (const float*)d_in[5];
  const float* vlnb = (const float*)d_in[6];
  const float* Wproj= (const float*)d_in[7];
  const float* bproj= (const float*)d_in[8];
  float* out = (float*)d_out;

  char* ws = (char*)d_ws;
  __bf16* Wkv = (__bf16*)(ws);                 // 512*256*2   = 262144
  __bf16* Wp  = (__bf16*)(ws + 262144);        // 256*256*2   = 131072
  float*  kv  = (float*) (ws + 393216);        // 32768*4     = 131072
  __bf16* Wqe = (__bf16*)(ws + 524288);        // 8*256*256*2 = 1048576
  float*  beff= (float*) (ws + 1572864);       // 8*256*4     = 8192

  k0_prep <<<512, 256, 0, stream>>>(Wqkv, Wproj, Wkv, Wp, kv);
  k1a     <<<2048, 512, 0, stream>>>(x, Wkv, bqkv, klnw, klnb, vlnw, vlnb, kv);
  k2_weff <<<128, 256, 0, stream>>>(Wqkv, bqkv, kv, Wqe, beff);
  k3_fused<<<2048, 512, 0, stream>>>(x, Wqe, beff, Wp, bproj, out);
}

// Round 17
// 188.712 us; speedup vs baseline: 1.1288x; 1.0384x over previous
//
#include <hip/hip_runtime.h>
#include <hip/hip_bf16.h>
#include <math.h>

// qkv_attn: x[8,16384,256] fp32. kv = LN(k)^T LN(v)/HW folded into Wq (per batch).
// R17: R13 verbatim (best measured 192.5us; R14-16 falsified preload-removal,
// reg-cap-relax, one-barrier variants) + ONE change: k3's erff replaced with the
// branch-free Abramowitz-Stegun erf approximation (abs err 1.5e-7) to shorten the
// serial post-GEMM2 epilogue VALU tail.

#define EPSF 1e-5f

typedef __bf16 bf16x8 __attribute__((ext_vector_type(8)));
typedef __bf16 bf16x4 __attribute__((ext_vector_type(4)));
typedef float  f32x4  __attribute__((ext_vector_type(4)));

__device__ __forceinline__ float fast_erf(float z) {
  // Abramowitz-Stegun 7.1.26, branch-free; abs err <= 1.5e-7
  float az = fabsf(z);
  float t = __builtin_amdgcn_rcpf(1.f + 0.3275911f*az);
  float poly = t*(0.254829592f + t*(-0.284496736f + t*(1.421413741f +
               t*(-1.453152027f + t*1.061405429f))));
  float ef = 1.f - poly*__expf(-az*az);
  return (z < 0.f) ? -ef : ef;
}

// ---------------- K0: weight prep (fp32 -> bf16, de-interleave k/v rows), zero kv accum ----
__global__ void k0_prep(const float* __restrict__ Wqkv, const float* __restrict__ Wproj,
                        __bf16* __restrict__ Wkv, __bf16* __restrict__ Wp,
                        float* __restrict__ kv) {
  int idx = blockIdx.x * 256 + threadIdx.x;   // grid 512*256 = 131072
  if (idx < 32768) kv[idx] = 0.f;             // kv accumulator [8][16][16][16]
  {
    int r = idx >> 8, c = idx & 255;
    int half = r >> 8;          // 0:k 1:v
    int rr = r & 255;
    int h = rr >> 4, d = rr & 15;
    Wkv[idx] = (__bf16)Wqkv[(h*48 + 16 + half*16 + d)*256 + c];
  }
  if (idx < 65536) Wp[idx] = (__bf16)Wproj[idx];
}

// ---------------- K1a: k,v GEMM + LN + local kv reduction (R13 verbatim) ----------------
__launch_bounds__(512, 4)
__global__ void k1a(const float* __restrict__ x, const __bf16* __restrict__ Wkv,
                    const float* __restrict__ bqkv,
                    const float* __restrict__ klnw, const float* __restrict__ klnb,
                    const float* __restrict__ vlnw, const float* __restrict__ vlnb,
                    float* __restrict__ kvout) {
  __shared__ __align__(16) char smem[70656];   // xs[64][264] (33792) | tTk 8x[32][72] (36864)
  __bf16 (*xs)[264] = reinterpret_cast<__bf16(*)[264]>(smem);
  const int tid = threadIdx.x;
  const int w = tid >> 6, l = tid & 63, lr = l & 15, g = l >> 4;
  __bf16 (*tTk)[72] = reinterpret_cast<__bf16(*)[72]>(smem + 33792 + w*4608); // [c 32][r 72]
  __bf16 (*tTv)[64] = reinterpret_cast<__bf16(*)[64]>(smem + w*4096);         // [c 32][r 64] swz

  const long row0 = (long)blockIdx.x * 64;
  const int b = (int)(row0 >> 14);

  #pragma unroll
  for (int i = 0; i < 8; ++i) {
    int idx = tid + i*512;
    int r = idx >> 6, c4 = (idx & 63) << 2;
    f32x4 v = *reinterpret_cast<const f32x4*>(x + (row0 + r)*256 + c4);
    bf16x4 pk; pk[0]=(__bf16)v[0]; pk[1]=(__bf16)v[1]; pk[2]=(__bf16)v[2]; pk[3]=(__bf16)v[3];
    *reinterpret_cast<bf16x4*>(&xs[r][c4]) = pk;
  }

  bf16x8 wk[2][8];
  #pragma unroll
  for (int cb=0;cb<2;cb++) {
    const __bf16* wp = Wkv + (size_t)(w*32 + cb*16 + lr)*256 + g*8;
    #pragma unroll
    for (int kc=0;kc<8;kc++) wk[cb][kc] = *reinterpret_cast<const bf16x8*>(wp + kc*32);
  }
  __syncthreads();

  f32x4 acc[2][4];
  for (int cb=0;cb<2;cb++) for (int rb=0;rb<4;rb++)
    for (int j=0;j<4;j++) acc[cb][rb][j]=0.f;
  #pragma unroll
  for (int kc = 0; kc < 8; ++kc) {
    const int kb = kc*32 + g*8;
    bf16x8 bf_[4];
    #pragma unroll
    for (int rb=0;rb<4;rb++)
      bf_[rb] = *reinterpret_cast<const bf16x8*>(&xs[rb*16+lr][kb]);
    #pragma unroll
    for (int cb=0;cb<2;cb++)
      #pragma unroll
      for (int rb=0;rb<4;rb++)
        acc[cb][rb] = __builtin_amdgcn_mfma_f32_16x16x32_bf16(wk[cb][kc], bf_[rb], acc[cb][rb], 0,0,0);
  }

  bf16x8 wv[2][8];
  #pragma unroll
  for (int cb=0;cb<2;cb++) {
    const __bf16* wp = Wkv + (size_t)(256 + w*32 + cb*16 + lr)*256 + g*8;
    #pragma unroll
    for (int kc=0;kc<8;kc++) wv[cb][kc] = *reinterpret_cast<const bf16x8*>(wp + kc*32);
  }

  // ---- pass 0 LN-k -> tTk (private region, no barrier needed) ----
  #pragma unroll
  for (int cb=0;cb<2;cb++) {
    const int h = 2*w + cb;
    const f32x4 bb  = *reinterpret_cast<const f32x4*>(bqkv + h*48 + 16 + 4*g);
    const f32x4 lwv = *reinterpret_cast<const f32x4*>(klnw + h*16 + 4*g);
    const f32x4 lbv = *reinterpret_cast<const f32x4*>(klnb + h*16 + 4*g);
    #pragma unroll
    for (int rb=0;rb<4;rb++) {
      float v0 = acc[cb][rb][0] + bb[0];
      float v1 = acc[cb][rb][1] + bb[1];
      float v2 = acc[cb][rb][2] + bb[2];
      float v3 = acc[cb][rb][3] + bb[3];
      float sum = v0+v1+v2+v3;
      sum += __shfl_xor(sum, 16); sum += __shfl_xor(sum, 32);
      const float mu = sum * 0.0625f;
      const float d0=v0-mu, d1=v1-mu, d2=v2-mu, d3=v3-mu;
      float q = d0*d0 + d1*d1 + d2*d2 + d3*d3;
      q += __shfl_xor(q, 16); q += __shfl_xor(q, 32);
      const float sc = __frsqrt_rn(q * (1.f/15.f));   // 1/(std+eps) ~ rsqrt(var)
      const int rr = rb*16 + lr;
      tTk[cb*16 + 4*g+0][rr] = (__bf16)(lwv[0]*d0*sc + lbv[0]);
      tTk[cb*16 + 4*g+1][rr] = (__bf16)(lwv[1]*d1*sc + lbv[1]);
      tTk[cb*16 + 4*g+2][rr] = (__bf16)(lwv[2]*d2*sc + lbv[2]);
      tTk[cb*16 + 4*g+3][rr] = (__bf16)(lwv[3]*d3*sc + lbv[3]);
    }
  }

  // ---- pass 1 (v) GEMM ----
  for (int cb=0;cb<2;cb++) for (int rb=0;rb<4;rb++)
    for (int j=0;j<4;j++) acc[cb][rb][j]=0.f;
  #pragma unroll
  for (int kc = 0; kc < 8; ++kc) {
    const int kb = kc*32 + g*8;
    bf16x8 bf_[4];
    #pragma unroll
    for (int rb=0;rb<4;rb++)
      bf_[rb] = *reinterpret_cast<const bf16x8*>(&xs[rb*16+lr][kb]);
    #pragma unroll
    for (int cb=0;cb<2;cb++)
      #pragma unroll
      for (int rb=0;rb<4;rb++)
        acc[cb][rb] = __builtin_amdgcn_mfma_f32_16x16x32_bf16(wv[cb][kc], bf_[rb], acc[cb][rb], 0,0,0);
  }

  // ---- LN-v arithmetic hoisted above the barrier: results packed into regs ----
  bf16x4 vpk[2][4];
  #pragma unroll
  for (int cb=0;cb<2;cb++) {
    const int h = 2*w + cb;
    const f32x4 bb  = *reinterpret_cast<const f32x4*>(bqkv + h*48 + 32 + 4*g);
    const f32x4 lwv = *reinterpret_cast<const f32x4*>(vlnw + h*16 + 4*g);
    const f32x4 lbv = *reinterpret_cast<const f32x4*>(vlnb + h*16 + 4*g);
    #pragma unroll
    for (int rb=0;rb<4;rb++) {
      float v0 = acc[cb][rb][0] + bb[0];
      float v1 = acc[cb][rb][1] + bb[1];
      float v2 = acc[cb][rb][2] + bb[2];
      float v3 = acc[cb][rb][3] + bb[3];
      float sum = v0+v1+v2+v3;
      sum += __shfl_xor(sum, 16); sum += __shfl_xor(sum, 32);
      const float mu = sum * 0.0625f;
      const float d0=v0-mu, d1=v1-mu, d2=v2-mu, d3=v3-mu;
      float q = d0*d0 + d1*d1 + d2*d2 + d3*d3;
      q += __shfl_xor(q, 16); q += __shfl_xor(q, 32);
      const float sc = __frsqrt_rn(q * (1.f/15.f));
      vpk[cb][rb][0] = (__bf16)(lwv[0]*d0*sc + lbv[0]);
      vpk[cb][rb][1] = (__bf16)(lwv[1]*d1*sc + lbv[1]);
      vpk[cb][rb][2] = (__bf16)(lwv[2]*d2*sc + lbv[2]);
      vpk[cb][rb][3] = (__bf16)(lwv[3]*d3*sc + lbv[3]);
    }
  }

  __syncthreads();   // WAR: all waves done reading xs; its space becomes tTv

  #pragma unroll
  for (int cb=0;cb<2;cb++) {
    #pragma unroll
    for (int rb=0;rb<4;rb++) {
      const int rr = rb*16 + lr;
      tTv[cb*16 + 4*g+0][rr ^ (((4*g+0)&7)<<3)] = vpk[cb][rb][0];
      tTv[cb*16 + 4*g+1][rr ^ (((4*g+1)&7)<<3)] = vpk[cb][rb][1];
      tTv[cb*16 + 4*g+2][rr ^ (((4*g+2)&7)<<3)] = vpk[cb][rb][2];
      tTv[cb*16 + 4*g+3][rr ^ (((4*g+3)&7)<<3)] = vpk[cb][rb][3];
    }
  }

  #pragma unroll
  for (int hh=0; hh<2; ++hh) {
    f32x4 c; c[0]=0.f; c[1]=0.f; c[2]=0.f; c[3]=0.f;
    #pragma unroll
    for (int ch=0; ch<2; ++ch) {
      const int s = ch*32 + g*8;
      bf16x8 a  = *reinterpret_cast<const bf16x8*>(&tTk[hh*16 + lr][s]);
      bf16x8 bv = *reinterpret_cast<const bf16x8*>(&tTv[hh*16 + lr][s ^ ((lr&7)<<3)]);
      c = __builtin_amdgcn_mfma_f32_16x16x32_bf16(a, bv, c, 0,0,0);
    }
    float* dst = kvout + ((size_t)(b*16 + 2*w + hh) << 8);
    #pragma unroll
    for (int j=0;j<4;j++)
      atomicAdd(dst + (4*g+j)*16 + lr, c[j]);
  }
}

// ---------------- K2: Wq_eff[b][h*16+e][c] = sum_d kv[b,h,d,e]/HW * Wq[h*48+d][c] ----------
__global__ void k2_weff(const float* __restrict__ Wqkv, const float* __restrict__ bqkv,
                        const float* __restrict__ kvin,
                        __bf16* __restrict__ Wqe, float* __restrict__ beff) {
  const int b = blockIdx.x >> 4, h = blockIdx.x & 15;
  const int c = threadIdx.x;
  __shared__ float kvs[16][16]; // [d][e]
  kvs[c >> 4][c & 15] = kvin[(b*16 + h)*256 + c] * (1.f/16384.f);
  __syncthreads();
  #pragma unroll 4
  for (int e=0;e<16;e++) {
    float acc = 0.f;
    #pragma unroll
    for (int d=0; d<16; d++)
      acc += kvs[d][e] * Wqkv[(h*48 + d)*256 + c];
    Wqe[((size_t)b*256 + h*16 + e)*256 + c] = (__bf16)acc;
  }
  if (c < 16) {
    float acc = 0.f;
    #pragma unroll
    for (int d=0; d<16; d++) acc += kvs[d][c] * bqkv[h*48 + d];
    beff[b*256 + h*16 + c] = acc;
  }
}

// ---------------- K3: fused o = x@Wq_eff^T; ret = o+beff+x -> rs; proj = ret@Wp^T;
//                  y = fast_gelu(proj+bp) + x(xs), staged through LDS ----------
__launch_bounds__(512, 4)
__global__ void k3_fused(const float* __restrict__ x, const __bf16* __restrict__ Wqe,
                         const float* __restrict__ beff, const __bf16* __restrict__ Wp,
                         const float* __restrict__ bproj, float* __restrict__ out) {
  __shared__ __align__(16) __bf16 xs[64][264];
  __shared__ __align__(16) char rsraw[33792];
  __bf16 (*rs)[264] = reinterpret_cast<__bf16(*)[264]>(rsraw);
  float  (*fst)[260] = reinterpret_cast<float(*)[260]>(rsraw);   // 32*260*4 = 33280 <= 33792
  const int tid = threadIdx.x;
  const long browg = (long)blockIdx.x * 64;
  const int b = (int)(browg >> 14);
  const int w = tid>>6, l = tid&63, lr = l&15, g = l>>4;

  #pragma unroll
  for (int i = 0; i < 8; ++i) {
    int idx = tid + i*512;
    int r = idx >> 6, c4 = (idx & 63) << 2;
    f32x4 v = *reinterpret_cast<const f32x4*>(x + (browg + r)*256 + c4);
    bf16x4 pk; pk[0]=(__bf16)v[0]; pk[1]=(__bf16)v[1]; pk[2]=(__bf16)v[2]; pk[3]=(__bf16)v[3];
    *reinterpret_cast<bf16x4*>(&xs[r][c4]) = pk;
  }

  const __bf16* Bq = Wqe + (size_t)b*65536;
  bf16x8 wq[2][8];
  #pragma unroll
  for (int cb=0;cb<2;cb++) {
    const __bf16* wp = Bq + (size_t)(w*32 + cb*16 + lr)*256 + g*8;
    #pragma unroll
    for (int kc=0;kc<8;kc++) wq[cb][kc] = *reinterpret_cast<const bf16x8*>(wp + kc*32);
  }
  __syncthreads();

  f32x4 acc[2][4];
  for (int cb=0;cb<2;cb++) for (int rb=0;rb<4;rb++)
    for (int j=0;j<4;j++) acc[cb][rb][j]=0.f;
  #pragma unroll
  for (int kc=0;kc<8;kc++) {
    const int kb = kc*32 + g*8;
    bf16x8 bf_[4];
    #pragma unroll
    for (int rb=0;rb<4;rb++)
      bf_[rb] = *reinterpret_cast<const bf16x8*>(&xs[rb*16+lr][kb]);
    #pragma unroll
    for (int cb=0;cb<2;cb++)
      #pragma unroll
      for (int rb=0;rb<4;rb++)
        acc[cb][rb] = __builtin_amdgcn_mfma_f32_16x16x32_bf16(wq[cb][kc], bf_[rb], acc[cb][rb], 0,0,0);
  }

  bf16x8 wpj[2][8];
  #pragma unroll
  for (int cb=0;cb<2;cb++) {
    const __bf16* wp = Wp + (size_t)(w*32 + cb*16 + lr)*256 + g*8;
    #pragma unroll
    for (int kc=0;kc<8;kc++) wpj[cb][kc] = *reinterpret_cast<const bf16x8*>(wp + kc*32);
  }

  // ret = o + beff + x -> rs
  #pragma unroll
  for (int cb=0;cb<2;cb++) {
    const int c0 = w*32 + cb*16 + 4*g;
    const f32x4 be = *reinterpret_cast<const f32x4*>(beff + b*256 + c0);
    #pragma unroll
    for (int rb=0;rb<4;rb++) {
      const int r = rb*16 + lr;
      bf16x4 xv = *reinterpret_cast<const bf16x4*>(&xs[r][c0]);
      bf16x4 pk;
      #pragma unroll
      for (int j=0;j<4;j++)
        pk[j] = (__bf16)(acc[cb][rb][j] + be[j] + (float)xv[j]);
      *reinterpret_cast<bf16x4*>(&rs[r][c0]) = pk;
    }
  }
  __syncthreads();

  f32x4 acc2[2][4];
  for (int cb=0;cb<2;cb++) for (int rb=0;rb<4;rb++)
    for (int j=0;j<4;j++) acc2[cb][rb][j]=0.f;
  #pragma unroll
  for (int kc=0;kc<8;kc++) {
    const int kb = kc*32 + g*8;
    bf16x8 bf_[4];
    #pragma unroll
    for (int rb=0;rb<4;rb++)
      bf_[rb] = *reinterpret_cast<const bf16x8*>(&rs[rb*16+lr][kb]);
    #pragma unroll
    for (int cb=0;cb<2;cb++)
      #pragma unroll
      for (int rb=0;rb<4;rb++)
        acc2[cb][rb] = __builtin_amdgcn_mfma_f32_16x16x32_bf16(wpj[cb][kc], bf_[rb], acc2[cb][rb], 0,0,0);
  }
  __syncthreads();   // all GEMM2 reads of rs done; rs region becomes fst

  #pragma unroll
  for (int half=0; half<2; ++half) {
    #pragma unroll
    for (int cb=0;cb<2;cb++) {
      const int c0 = w*32 + cb*16 + 4*g;
      const f32x4 bp4 = *reinterpret_cast<const f32x4*>(bproj + c0);
      #pragma unroll
      for (int rbh=0;rbh<2;rbh++) {
        const int rb = half*2 + rbh;
        const int r = rb*16 + lr;
        bf16x4 xv = *reinterpret_cast<const bf16x4*>(&xs[r][c0]);
        f32x4 o;
        #pragma unroll
        for (int j=0;j<4;j++) {
          float z = acc2[cb][rb][j] + bp4[j];
          o[j] = 0.5f*z*(1.f + fast_erf(z*0.70710678118f)) + (float)xv[j];
        }
        *reinterpret_cast<f32x4*>(&fst[r - half*32][c0]) = o;
      }
    }
    __syncthreads();
    #pragma unroll
    for (int i=0;i<4;i++) {
      int idx = tid + i*512;               // 2048 chunks = 32 rows * 64
      int r32 = idx >> 6, c4 = (idx & 63) << 2;
      f32x4 v = *reinterpret_cast<const f32x4*>(&fst[r32][c4]);
      *reinterpret_cast<f32x4*>(out + (browg + half*32 + r32)*256 + c4) = v;
    }
    if (half == 0) __syncthreads();
  }
}

extern "C" void kernel_launch(void* const* d_in, const int* in_sizes, int n_in,
                              void* d_out, int out_size, void* d_ws, size_t ws_size,
                              hipStream_t stream) {
  const float* x    = (const float*)d_in[0];
  const float* Wqkv = (const float*)d_in[1];
  const float* bqkv = (const float*)d_in[2];
  const float* klnw = (const float*)d_in[3];
  const float* klnb = (const float*)d_in[4];
  const float* vlnw = (const float*)d_in[5];
  const float* vlnb = (const float*)d_in[6];
  const float* Wproj= (const float*)d_in[7];
  const float* bproj= (const float*)d_in[8];
  float* out = (float*)d_out;

  char* ws = (char*)d_ws;
  __bf16* Wkv = (__bf16*)(ws);                 // 512*256*2   = 262144
  __bf16* Wp  = (__bf16*)(ws + 262144);        // 256*256*2   = 131072
  float*  kv  = (float*) (ws + 393216);        // 32768*4     = 131072
  __bf16* Wqe = (__bf16*)(ws + 524288);        // 8*256*256*2 = 1048576
  float*  beff= (float*) (ws + 1572864);       // 8*256*4     = 8192

  k0_prep <<<512, 256, 0, stream>>>(Wqkv, Wproj, Wkv, Wp, kv);
  k1a     <<<2048, 512, 0, stream>>>(x, Wkv, bqkv, klnw, klnb, vlnw, vlnb, kv);
  k2_weff <<<128, 256, 0, stream>>>(Wqkv, bqkv, kv, Wqe, beff);
  k3_fused<<<2048, 512, 0, stream>>>(x, Wqe, beff, Wp, bproj, out);
}